// Round 8
// baseline (170.161 us; speedup 1.0000x reference)
//
#include <hip/hip_runtime.h>
#include <math.h>

#define N_NODES 20000
#define N_EDGES 160000

#define PI_F 3.14159265358979323846f
#define LN2_F 0.69314718055994530942f

#define W1PK 43008         // 21 ksteps * 4 colfrags * 64 lanes * 8 (ushort units)
#define W23PK 4096         // 2 ksteps  * 4 * 64 * 8
#define WPK_LAYER 51200    // per-layer packed weights (ushort units)
#define XROW 680           // LDS X row stride in u16 (340 dwords)

typedef short short8v __attribute__((ext_vector_type(8)));
typedef float f32x4 __attribute__((ext_vector_type(4)));
typedef unsigned short u16;

__device__ __forceinline__ float sspf(float x) {
    return fmaxf(x, 0.0f) + log1pf(expf(-fabsf(x))) - LN2_F;
}
// round-to-nearest-even f32 -> bf16
__device__ __forceinline__ u16 f2bf(float f) {
    unsigned int u = __float_as_uint(f);
    return (u16)((u + 0x7fffu + ((u >> 16) & 1u)) >> 16);
}
__device__ __forceinline__ unsigned int pk2(float a, float b) {
    return (unsigned int)f2bf(a) | ((unsigned int)f2bf(b) << 16);
}
__device__ __forceinline__ float bflo(unsigned int u) { return __uint_as_float(u << 16); }
__device__ __forceinline__ float bfhi(unsigned int u) { return __uint_as_float(u & 0xffff0000u); }

// ---------------------------------------------------------------------------
// w[e][es][16] (bf16, 64 u16/edge): element m (0..9) of block es is
// sw*rb[2es+m/5]*bo[m%5]; slots 10..15 zero. Lane-aligned for phase A.
// ---------------------------------------------------------------------------
__global__ __launch_bounds__(256) void edge_w_kernel(
    const float* __restrict__ dist,
    const float* __restrict__ sw,
    const float* __restrict__ bo,
    u16* __restrict__ wedge)
{
    int e = blockIdx.x * blockDim.x + threadIdx.x;
    if (e >= N_EDGES) return;
    float r = dist[e];
    float c = sqrtf(2.0f / 5.0f) / r * sw[e];
    float rbv[8];
    #pragma unroll
    for (int n = 0; n < 8; ++n)
        rbv[n] = c * sinf((float)(n + 1) * PI_F * r * 0.2f);
    float bov[5];
    #pragma unroll
    for (int b = 0; b < 5; ++b) bov[b] = bo[(size_t)e * 5 + b];

    unsigned int* out = reinterpret_cast<unsigned int*>(wedge + ((size_t)e << 6));
    #pragma unroll
    for (int es = 0; es < 4; ++es) {
        float w0 = rbv[2 * es] * bov[0];
        float w1 = rbv[2 * es] * bov[1];
        float w2 = rbv[2 * es] * bov[2];
        float w3 = rbv[2 * es] * bov[3];
        float w4 = rbv[2 * es] * bov[4];
        float w5 = rbv[2 * es + 1] * bov[0];
        float w6 = rbv[2 * es + 1] * bov[1];
        float w7 = rbv[2 * es + 1] * bov[2];
        float w8 = rbv[2 * es + 1] * bov[3];
        float w9 = rbv[2 * es + 1] * bov[4];
        uint4 pa, pb;
        pa.x = pk2(w0, w1); pa.y = pk2(w2, w3);
        pa.z = pk2(w4, w5); pa.w = pk2(w6, w7);
        pb.x = pk2(w8, w9); pb.y = 0u; pb.z = 0u; pb.w = 0u;
        *reinterpret_cast<uint4*>(out + es * 8) = pa;
        *reinterpret_cast<uint4*>(out + es * 8 + 4) = pb;
    }
}

// ---------------------------------------------------------------------------
// CSR offsets from sorted edge_src
// ---------------------------------------------------------------------------
__global__ __launch_bounds__(256) void row_start_kernel(
    const int* __restrict__ src, int* __restrict__ row)
{
    int i = blockIdx.x * blockDim.x + threadIdx.x;
    if (i > N_NODES) return;
    int lo = 0, hi = N_EDGES;
    while (lo < hi) {
        int mid = (lo + hi) >> 1;
        if (src[mid] < i) lo = mid + 1; else hi = mid;
    }
    row[i] = lo;
}

// ---------------------------------------------------------------------------
// xi = W_species[species]
// ---------------------------------------------------------------------------
__global__ __launch_bounds__(256) void xi_init_kernel(
    const int* __restrict__ species,
    const float* __restrict__ Wsp,
    float* __restrict__ xi)
{
    int idx = blockIdx.x * blockDim.x + threadIdx.x;
    if (idx >= N_NODES * 16) return;
    int node = idx >> 4;
    int c4 = idx & 15;
    int sp = species[node];
    reinterpret_cast<float4*>(xi)[idx] =
        reinterpret_cast<const float4*>(Wsp + (size_t)sp * 64)[c4];
}

// ---------------------------------------------------------------------------
// Pack FC weights -> bf16 B-fragment layout for mfma_f32_16x16x32_bf16.
// ---------------------------------------------------------------------------
__global__ __launch_bounds__(256) void pack_w_kernel(
    const float* __restrict__ fcW1,
    const float* __restrict__ fcW2,
    const float* __restrict__ fcW3,
    u16* __restrict__ Wpk)
{
    int idx = blockIdx.x * 256 + threadIdx.x;
    if (idx >= 3 * WPK_LAYER) return;
    int layer = idx / WPK_LAYER;
    int r = idx - layer * WPK_LAYER;
    float val = 0.0f;
    if (r < W1PK) {
        int e = r;
        int j = e & 7, lane = (e >> 3) & 63, c16 = (e >> 9) & 3, ks = e >> 11;
        int k = ks * 32 + (lane >> 4) * 8 + j;
        int colm = c16 * 16 + (lane & 15);
        if (k < 640) {
            int ss = k / 40, rem = k - ss * 40;
            int nn = rem / 5, bb = rem - nn * 5;
            val = fcW1[(size_t)layer * 656 * 64 + (size_t)(nn * 80 + ss * 5 + bb) * 64 + colm];
        } else if (k < 656) {
            val = fcW1[(size_t)layer * 656 * 64 + (size_t)k * 64 + colm];
        }
    } else {
        bool is2 = (r < W1PK + W23PK);
        const float* W = is2 ? fcW2 : fcW3;
        int e = is2 ? (r - W1PK) : (r - W1PK - W23PK);
        int j = e & 7, lane = (e >> 3) & 63, c16 = (e >> 9) & 3, ks = e >> 11;
        int k = ks * 32 + (lane >> 4) * 8 + j;
        int colm = c16 * 16 + (lane & 15);
        val = W[(size_t)layer * 64 * 64 + (size_t)k * 64 + colm];
    }
    Wpk[(size_t)layer * WPK_LAYER + r] = f2bf(val);
}

// ---------------------------------------------------------------------------
// h = xi @ Wl[l] + bl[l]   (N x 32).  float4 stores.
// ---------------------------------------------------------------------------
__global__ __launch_bounds__(256) void h_kernel(
    const float* __restrict__ xi,
    const float* __restrict__ Wl,
    const float* __restrict__ bl,
    float* __restrict__ h)
{
    __shared__ float xs[32 * 64];
    __shared__ float ws[64 * 32];
    int tid = threadIdx.x;
    int nb = blockIdx.x * 32;

    const float4* xsrc = reinterpret_cast<const float4*>(xi + (size_t)nb * 64);
    float4* xd = reinterpret_cast<float4*>(xs);
    #pragma unroll
    for (int i = 0; i < 2; ++i) xd[tid + i * 256] = xsrc[tid + i * 256];
    const float4* wsrc = reinterpret_cast<const float4*>(Wl);
    float4* wd = reinterpret_cast<float4*>(ws);
    #pragma unroll
    for (int i = 0; i < 2; ++i) wd[tid + i * 256] = wsrc[tid + i * 256];
    __syncthreads();

    int c4g = tid & 7;
    int nrow = tid >> 3;
    float4 acc = *reinterpret_cast<const float4*>(bl + c4g * 4);
    const float* xr = xs + nrow * 64;
    #pragma unroll 8
    for (int j = 0; j < 64; ++j) {
        float xv = xr[j];
        float4 wv = *reinterpret_cast<const float4*>(ws + j * 32 + c4g * 4);
        acc.x = fmaf(xv, wv.x, acc.x);
        acc.y = fmaf(xv, wv.y, acc.y);
        acc.z = fmaf(xv, wv.z, acc.z);
        acc.w = fmaf(xv, wv.w, acc.w);
    }
    *reinterpret_cast<float4*>(h + (size_t)(nb + nrow) * 32 + c4g * 4) = acc;
}

// ---------------------------------------------------------------------------
// FUSED agg + FC chain. Block = 256 thr = 4 waves; 16 nodes per block.
// Phase A (v2): lane (s,es) OWNS features f = s*40+10es+m -> no cross-lane
//   reduce at all. The wave's 4 nodes are interleaved in one edge loop
//   (4 independent dst->h gather chains; wave-uniform branches).
//   acc arrays statically indexed everywhere (rule #20).
// Phase B: MFMA FC1(K=672, zero-padded)/FC2/FC3 + xi residual.
// ---------------------------------------------------------------------------
__global__ __launch_bounds__(256) void agg_fc_kernel(
    const u16* __restrict__ wedge,          // E x 64 u16 (w, lane-aligned)
    const int* __restrict__ row,
    const int* __restrict__ dst,
    const float* __restrict__ h,            // N x 32
    const u16* __restrict__ Wpk,            // layer's packed weights
    const float* __restrict__ b1,
    const float* __restrict__ b2,
    const float* __restrict__ b3,
    float* __restrict__ xi)
{
    __shared__ __align__(16) u16 Xs[16][XROW];   // 21760 B
    __shared__ __align__(16) u16 Y1[16 * 72];    //  2304 B
    __shared__ __align__(16) u16 Y2[16 * 72];    //  2304 B
    __shared__ __align__(16) float Yo[16 * 68];  //  4352 B

    int tid = threadIdx.x;
    int wv = tid >> 6;
    int lane = tid & 63;
    int s = lane & 15;
    int es = lane >> 4;
    int n0 = blockIdx.x * 16;
    int base = n0 + (wv << 2);

    // ======== Phase A: 4-node interleaved aggregation ========
    int r0 = row[base], r1 = row[base + 1], r2 = row[base + 2],
        r3 = row[base + 3], r4 = row[base + 4];
    int eb0 = r0, ee0 = r1;
    int eb1 = r1, ee1 = r2;
    int eb2 = r2, ee2 = r3;
    int eb3 = r3, ee3 = r4;

    float a0[10], a1[10], a2[10], a3[10];
    #pragma unroll
    for (int m = 0; m < 10; ++m) { a0[m] = 0.f; a1[m] = 0.f; a2[m] = 0.f; a3[m] = 0.f; }

    int d0 = ee0 - eb0, d1 = ee1 - eb1, d2 = ee2 - eb2, d3 = ee3 - eb3;
    int iters = max(max(d0, d1), max(d2, d3));

#define PROC(eb, ee, at)                                                     \
    {                                                                        \
        int e = (eb) + i;                                                    \
        if (e < (ee)) {                                                      \
            int d = dst[e];                                                  \
            float mi = h[(size_t)d * 32 + 16 + s];                           \
            const u16* wp = wedge + ((size_t)e << 6) + (es << 4);            \
            uint4 wa = *reinterpret_cast<const uint4*>(wp);                  \
            unsigned int wb = *reinterpret_cast<const unsigned int*>(wp + 8);\
            at[0] = fmaf(bflo(wa.x), mi, at[0]);                             \
            at[1] = fmaf(bfhi(wa.x), mi, at[1]);                             \
            at[2] = fmaf(bflo(wa.y), mi, at[2]);                             \
            at[3] = fmaf(bfhi(wa.y), mi, at[3]);                             \
            at[4] = fmaf(bflo(wa.z), mi, at[4]);                             \
            at[5] = fmaf(bfhi(wa.z), mi, at[5]);                             \
            at[6] = fmaf(bflo(wa.w), mi, at[6]);                             \
            at[7] = fmaf(bfhi(wa.w), mi, at[7]);                             \
            at[8] = fmaf(bflo(wb), mi, at[8]);                               \
            at[9] = fmaf(bfhi(wb), mi, at[9]);                               \
        }                                                                    \
    }

    for (int i = 0; i < iters; ++i) {
        PROC(eb0, ee0, a0)
        PROC(eb1, ee1, a1)
        PROC(eb2, ee2, a2)
        PROC(eb3, ee3, a3)
    }
#undef PROC

    // ---- stage rows into LDS (lane owns dwords s*20 + es*5 + 0..4) ----
#define STAGE(t, at)                                                         \
    {                                                                        \
        unsigned int* rb = reinterpret_cast<unsigned int*>(&Xs[(wv << 2) + (t)][0]); \
        unsigned int* op = rb + (s * 20 + es * 5);                           \
        op[0] = pk2(at[0], at[1]);                                           \
        op[1] = pk2(at[2], at[3]);                                           \
        op[2] = pk2(at[4], at[5]);                                           \
        op[3] = pk2(at[6], at[7]);                                           \
        op[4] = pk2(at[8], at[9]);                                           \
        int wid = base + (t);                                                \
        if (es == 2 && s < 8) {                                              \
            float v0 = h[(size_t)wid * 32 + 2 * s];                          \
            float v1 = h[(size_t)wid * 32 + 2 * s + 1];                      \
            rb[320 + s] = pk2(v0, v1);                                       \
        }                                                                    \
        if (es == 3 && s < 8)                                                \
            rb[328 + s] = 0u;                                                \
    }
    STAGE(0, a0)
    STAGE(1, a1)
    STAGE(2, a2)
    STAGE(3, a3)
#undef STAGE
    __syncthreads();

    // ======== Phase B: MFMA FC chain ========
    int w = wv;
    int l = lane;
    int lrow = l & 15;
    int lk = l >> 4;
    int col = w * 16 + lrow;

    const u16* Wpk1 = Wpk;
    const u16* Wpk2 = Wpk + W1PK;
    const u16* Wpk3 = Wpk + W1PK + W23PK;

    // ---- FC1: K = 672 (cols 656..671 zero x zero-packed W) ----
    f32x4 acc;
    {
        float bv = b1[col];
        acc[0] = bv; acc[1] = bv; acc[2] = bv; acc[3] = bv;
    }
    const u16* wp = Wpk1 + ((size_t)w * 64 + l) * 8;
    #pragma unroll
    for (int ks = 0; ks < 21; ++ks) {
        short8v a = *reinterpret_cast<const short8v*>(&Xs[lrow][ks * 32 + lk * 8]);
        short8v b = *reinterpret_cast<const short8v*>(wp + (size_t)ks * 2048);
        acc = __builtin_amdgcn_mfma_f32_16x16x32_bf16(a, b, acc, 0, 0, 0);
    }
    #pragma unroll
    for (int q = 0; q < 4; ++q)
        Y1[(lk * 4 + q) * 72 + col] = f2bf(sspf(acc[q]));
    __syncthreads();

    // ---- FC2: K = 64 ----
    {
        float bv = b2[col];
        acc[0] = bv; acc[1] = bv; acc[2] = bv; acc[3] = bv;
    }
    #pragma unroll
    for (int ks = 0; ks < 2; ++ks) {
        short8v a = *reinterpret_cast<const short8v*>(&Y1[lrow * 72 + ks * 32 + lk * 8]);
        short8v b = *reinterpret_cast<const short8v*>(Wpk2 + ((size_t)(ks * 4 + w) * 64 + l) * 8);
        acc = __builtin_amdgcn_mfma_f32_16x16x32_bf16(a, b, acc, 0, 0, 0);
    }
    #pragma unroll
    for (int q = 0; q < 4; ++q)
        Y2[(lk * 4 + q) * 72 + col] = f2bf(sspf(acc[q]));
    __syncthreads();

    // ---- FC3: K = 64 ----
    {
        float bv = b3[col];
        acc[0] = bv; acc[1] = bv; acc[2] = bv; acc[3] = bv;
    }
    #pragma unroll
    for (int ks = 0; ks < 2; ++ks) {
        short8v a = *reinterpret_cast<const short8v*>(&Y2[lrow * 72 + ks * 32 + lk * 8]);
        short8v b = *reinterpret_cast<const short8v*>(Wpk3 + ((size_t)(ks * 4 + w) * 64 + l) * 8);
        acc = __builtin_amdgcn_mfma_f32_16x16x32_bf16(a, b, acc, 0, 0, 0);
    }
    #pragma unroll
    for (int q = 0; q < 4; ++q)
        Yo[(lk * 4 + q) * 68 + col] = acc[q];
    __syncthreads();

    // ---- residual update, float4 per lane ----
    {
        int rr = tid >> 4;
        int cc = tid & 15;
        float4 dv = *reinterpret_cast<const float4*>(Yo + rr * 68 + cc * 4);
        float4* xpn = reinterpret_cast<float4*>(xi + (size_t)(n0 + rr) * 64 + cc * 4);
        float4 o = *xpn;
        o.x += dv.x; o.y += dv.y; o.z += dv.z; o.w += dv.w;
        *xpn = o;
    }
}

// ---------------------------------------------------------------------------
extern "C" void kernel_launch(void* const* d_in, const int* in_sizes, int n_in,
                              void* d_out, int out_size, void* d_ws, size_t ws_size,
                              hipStream_t stream) {
    const int*   species = (const int*)d_in[0];
    const int*   esrc    = (const int*)d_in[1];
    const int*   edst    = (const int*)d_in[2];
    const float* dist    = (const float*)d_in[3];
    const float* sw      = (const float*)d_in[4];
    const float* bo      = (const float*)d_in[5];
    const float* Wsp     = (const float*)d_in[6];
    const float* Wl      = (const float*)d_in[7];
    const float* bl      = (const float*)d_in[8];
    const float* fcW1    = (const float*)d_in[9];
    const float* fcb1    = (const float*)d_in[10];
    const float* fcW2    = (const float*)d_in[11];
    const float* fcb2    = (const float*)d_in[12];
    const float* fcW3    = (const float*)d_in[13];
    const float* fcb3    = (const float*)d_in[14];
    float* xi = (float*)d_out;

    char* ws = (char*)d_ws;
    u16*   wedge = (u16*)ws;                    // 20,480,000 B
    int*   rowp  = (int*)(ws + 20480000);       //     80,128 B
    float* h     = (float*)(ws + 20560128);     //  2,560,000 B
    u16*   Wpk   = (u16*)(ws + 23120128);       //    307,200 B

    hipLaunchKernelGGL(edge_w_kernel, dim3(625), dim3(256), 0, stream,
                       dist, sw, bo, wedge);
    hipLaunchKernelGGL(row_start_kernel, dim3(79), dim3(256), 0, stream,
                       esrc, rowp);
    hipLaunchKernelGGL(xi_init_kernel, dim3(1250), dim3(256), 0, stream,
                       species, Wsp, xi);
    hipLaunchKernelGGL(pack_w_kernel, dim3(600), dim3(256), 0, stream,
                       fcW1, fcW2, fcW3, Wpk);

    for (int l = 0; l < 3; ++l) {
        hipLaunchKernelGGL(h_kernel, dim3(625), dim3(256), 0, stream,
                           xi, Wl + (size_t)l * 64 * 32, bl + (size_t)l * 32, h);
        hipLaunchKernelGGL(agg_fc_kernel, dim3(1250), dim3(256), 0, stream,
                           wedge, rowp, edst, h,
                           Wpk + (size_t)l * WPK_LAYER,
                           fcb1 + (size_t)l * 64, fcb2 + (size_t)l * 64,
                           fcb3 + (size_t)l * 64, xi);
    }
}